// Round 1
// baseline (487.479 us; speedup 1.0000x reference)
//
#include <hip/hip_runtime.h>

// Integrate-and-fire neuron, TBN layout, scan over T.
//   m_t = v_{t-1} + x_t ; y_t = (m_t >= 1.0f) ? 1 : 0 ; v_t = m_t - y_t
// Each thread owns 4 consecutive neurons (float4), carries v in registers,
// and walks t with stride BN/4 float4s (coalesced across lanes at each t).

#define T_STEPS 32

__global__ __launch_bounds__(256) void if_kernel(const float4* __restrict__ x,
                                                 float4* __restrict__ y,
                                                 int bn4) {
    int idx = blockIdx.x * blockDim.x + threadIdx.x;
    if (idx >= bn4) return;

    float4 v = make_float4(0.f, 0.f, 0.f, 0.f);

    const float4* xp = x + idx;
    float4* yp = y + idx;

#pragma unroll
    for (int t = 0; t < T_STEPS; ++t) {
        float4 xv = xp[(size_t)t * bn4];
        float4 m, out;
        m.x = v.x + xv.x;
        m.y = v.y + xv.y;
        m.z = v.z + xv.z;
        m.w = v.w + xv.w;
        out.x = (m.x >= 1.0f) ? 1.0f : 0.0f;
        out.y = (m.y >= 1.0f) ? 1.0f : 0.0f;
        out.z = (m.z >= 1.0f) ? 1.0f : 0.0f;
        out.w = (m.w >= 1.0f) ? 1.0f : 0.0f;
        v.x = m.x - out.x;
        v.y = m.y - out.y;
        v.z = m.z - out.z;
        v.w = m.w - out.w;
        yp[(size_t)t * bn4] = out;
    }
}

extern "C" void kernel_launch(void* const* d_in, const int* in_sizes, int n_in,
                              void* d_out, int out_size, void* d_ws, size_t ws_size,
                              hipStream_t stream) {
    const float* x = (const float*)d_in[0];
    float* y = (float*)d_out;

    int total = in_sizes[0];        // T*B*N = 67,108,864
    int bn = total / T_STEPS;       // B*N  =  2,097,152
    int bn4 = bn / 4;               //        524,288 float4 columns

    int block = 256;
    int grid = (bn4 + block - 1) / block;  // 2048 blocks

    if_kernel<<<grid, block, 0, stream>>>((const float4*)x, (float4*)y, bn4);
}

// Round 2
// 486.462 us; speedup vs baseline: 1.0021x; 1.0021x over previous
//
#include <hip/hip_runtime.h>

// Integrate-and-fire, TBN layout. One thread per 4 consecutive neurons.
// R2: explicit 8-deep load prefetch pipeline (the R1 codegen at 32 VGPRs
// kept only ~2 loads in flight -> latency-bound at 29% HBM peak), plus
// non-temporal stores for the write-once y stream.

typedef float v4f __attribute__((ext_vector_type(4)));

#define T_STEPS 32
#define PF 8   // prefetch depth: 8 float4 loads in flight = 32 VGPRs of buffer

__global__ __launch_bounds__(256, 8) void if_kernel(const v4f* __restrict__ x,
                                                    v4f* __restrict__ y,
                                                    int bn4) {
    int idx = blockIdx.x * blockDim.x + threadIdx.x;
    if (idx >= bn4) return;

    const v4f* xp = x + idx;
    v4f* yp = y + idx;

    // Prologue: fill the pipeline with PF independent loads.
    v4f buf[PF];
#pragma unroll
    for (int i = 0; i < PF; ++i)
        buf[i] = xp[(size_t)i * bn4];

    v4f v = (v4f){0.f, 0.f, 0.f, 0.f};

#pragma unroll
    for (int t = 0; t < T_STEPS; ++t) {
        v4f xv = buf[t % PF];
        // Refill the slot we just consumed (full unroll renames registers,
        // so this load issues immediately and retires PF iterations later).
        if (t + PF < T_STEPS)
            buf[t % PF] = xp[(size_t)(t + PF) * bn4];

        v4f m = v + xv;
        v4f out;
        out.x = (m.x >= 1.0f) ? 1.0f : 0.0f;
        out.y = (m.y >= 1.0f) ? 1.0f : 0.0f;
        out.z = (m.z >= 1.0f) ? 1.0f : 0.0f;
        out.w = (m.w >= 1.0f) ? 1.0f : 0.0f;
        v = m - out;

        // y is written once and never read -> non-temporal, no write-allocate.
        __builtin_nontemporal_store(out, yp + (size_t)t * bn4);
    }
}

extern "C" void kernel_launch(void* const* d_in, const int* in_sizes, int n_in,
                              void* d_out, int out_size, void* d_ws, size_t ws_size,
                              hipStream_t stream) {
    const float* x = (const float*)d_in[0];
    float* y = (float*)d_out;

    int total = in_sizes[0];        // T*B*N = 67,108,864
    int bn = total / T_STEPS;       // B*N  =  2,097,152
    int bn4 = bn / 4;               //        524,288 float4 columns

    int block = 256;
    int grid = (bn4 + block - 1) / block;  // 2048 blocks = 8 per CU

    if_kernel<<<grid, block, 0, stream>>>((const v4f*)x, (v4f*)y, bn4);
}

// Round 3
// 479.105 us; speedup vs baseline: 1.0175x; 1.0154x over previous
//
#include <hip/hip_runtime.h>

// Integrate-and-fire, TBN layout. One thread per 4 consecutive neurons.
// R3: R2's prefetch pipeline was collapsed by the scheduler (VGPR stayed 32 —
// loads sunk to uses). Pin issue order with asm-volatile memory fences so the
// 8-deep pipeline actually materializes: prologue issues 8 loads, each
// iteration refills the consumed slot, fence at iteration tail prevents
// sinking. Keeps ~8 KiB of loads in flight per wave.

typedef float v4f __attribute__((ext_vector_type(4)));

#define T_STEPS 32
#define PF 8   // prefetch depth (power of 2): 8 float4 = 32 VGPRs of buffer

__global__ __launch_bounds__(256, 8) void if_kernel(const v4f* __restrict__ x,
                                                    v4f* __restrict__ y,
                                                    int bn4) {
    int idx = blockIdx.x * blockDim.x + threadIdx.x;
    if (idx >= bn4) return;

    const v4f* xp = x + idx;
    v4f* yp = y + idx;

    // Prologue: fill the pipeline with PF independent loads.
    v4f buf[PF];
#pragma unroll
    for (int i = 0; i < PF; ++i)
        buf[i] = xp[(size_t)i * bn4];

    // Fence: all PF loads are issued before anything below is scheduled.
    asm volatile("" ::: "memory");

    v4f v = (v4f){0.f, 0.f, 0.f, 0.f};

#pragma unroll
    for (int t = 0; t < T_STEPS; ++t) {
        v4f xv = buf[t & (PF - 1)];

        // Refill the consumed slot; the tail fence keeps this load issued in
        // THIS iteration, retiring PF iterations later -> vmcnt(N>0) waits.
        if (t + PF < T_STEPS)
            buf[t & (PF - 1)] = xp[(size_t)(t + PF) * bn4];

        v4f m = v + xv;
        v4f out;
        out.x = (m.x >= 1.0f) ? 1.0f : 0.0f;
        out.y = (m.y >= 1.0f) ? 1.0f : 0.0f;
        out.z = (m.z >= 1.0f) ? 1.0f : 0.0f;
        out.w = (m.w >= 1.0f) ? 1.0f : 0.0f;
        v = m - out;

        // y is written once, never read -> non-temporal (no write-allocate;
        // R2 confirmed WRITE_SIZE drops to exactly 256 MiB).
        __builtin_nontemporal_store(out, yp + (size_t)t * bn4);

        // Iteration-tail fence: pin program order across iterations.
        asm volatile("" ::: "memory");
    }
}

extern "C" void kernel_launch(void* const* d_in, const int* in_sizes, int n_in,
                              void* d_out, int out_size, void* d_ws, size_t ws_size,
                              hipStream_t stream) {
    const float* x = (const float*)d_in[0];
    float* y = (float*)d_out;

    int total = in_sizes[0];        // T*B*N = 67,108,864
    int bn = total / T_STEPS;       // B*N  =  2,097,152
    int bn4 = bn / 4;               //        524,288 float4 columns

    int block = 256;
    int grid = (bn4 + block - 1) / block;  // 2048 blocks = 8 per CU

    if_kernel<<<grid, block, 0, stream>>>((const v4f*)x, (v4f*)y, bn4);
}

// Round 4
// 458.110 us; speedup vs baseline: 1.0641x; 1.0458x over previous
//
#include <hip/hip_runtime.h>

// Integrate-and-fire, TBN layout. One thread per 4 consecutive neurons.
// R4: the ~210us plateau (R1=R2=R3) is store-ack serialization: vmcnt counts
// stores too, in issue order, so each iteration's s_waitcnt vmcnt(0) before
// consuming load t also drains the previous iteration's STORE ack through a
// megabytes-deep write queue (~6.6us/iter observed). Fix: spikes are 1 bit.
// Pack all T=32 x 4 outputs into 4 uint32 bitmasks in the main loop (loads
// are then the ONLY vmem ops in the wait chain), expand + store everything
// in a wait-free epilogue burst.

typedef float v4f __attribute__((ext_vector_type(4)));

#define T_STEPS 32

__global__ __launch_bounds__(256, 8) void if_kernel(const v4f* __restrict__ x,
                                                    v4f* __restrict__ y,
                                                    int bn4) {
    int idx = blockIdx.x * blockDim.x + threadIdx.x;
    if (idx >= bn4) return;

    const v4f* xp = x + idx;

    float v0 = 0.f, v1 = 0.f, v2 = 0.f, v3 = 0.f;
    unsigned m0 = 0u, m1 = 0u, m2 = 0u, m3 = 0u;

    // Main loop: loads only — no store ever enters the vmcnt queue here.
#pragma unroll
    for (int t = 0; t < T_STEPS; ++t) {
        v4f xv = xp[(size_t)t * bn4];
        float a0 = v0 + xv.x;
        float a1 = v1 + xv.y;
        float a2 = v2 + xv.z;
        float a3 = v3 + xv.w;
        bool s0 = a0 >= 1.0f;
        bool s1 = a1 >= 1.0f;
        bool s2 = a2 >= 1.0f;
        bool s3 = a3 >= 1.0f;
        m0 |= (unsigned)s0 << t;
        m1 |= (unsigned)s1 << t;
        m2 |= (unsigned)s2 << t;
        m3 |= (unsigned)s3 << t;
        v0 = s0 ? a0 - 1.0f : a0;   // soft reset by subtraction
        v1 = s1 ? a1 - 1.0f : a1;
        v2 = s2 ? a2 - 1.0f : a2;
        v3 = s3 ? a3 - 1.0f : a3;
    }

    // Epilogue: expand bitmasks, store all 32 planes back-to-back.
    // Stores feed nothing -> no waitcnt anywhere in this loop.
    v4f* yp = y + idx;
#pragma unroll
    for (int t = 0; t < T_STEPS; ++t) {
        v4f out;
        out.x = ((m0 >> t) & 1u) ? 1.0f : 0.0f;
        out.y = ((m1 >> t) & 1u) ? 1.0f : 0.0f;
        out.z = ((m2 >> t) & 1u) ? 1.0f : 0.0f;
        out.w = ((m3 >> t) & 1u) ? 1.0f : 0.0f;
        // nt store: write-once stream, no write-allocate (R2: WRITE_SIZE
        // dropped to exactly 256 MiB ideal with nt).
        __builtin_nontemporal_store(out, yp + (size_t)t * bn4);
    }
}

extern "C" void kernel_launch(void* const* d_in, const int* in_sizes, int n_in,
                              void* d_out, int out_size, void* d_ws, size_t ws_size,
                              hipStream_t stream) {
    const float* x = (const float*)d_in[0];
    float* y = (float*)d_out;

    int total = in_sizes[0];        // T*B*N = 67,108,864
    int bn = total / T_STEPS;       // B*N  =  2,097,152
    int bn4 = bn / 4;               //        524,288 float4 columns

    int block = 256;
    int grid = (bn4 + block - 1) / block;  // 2048 blocks = 8 per CU

    if_kernel<<<grid, block, 0, stream>>>((const v4f*)x, (v4f*)y, bn4);
}